// Round 5
// baseline (161.032 us; speedup 1.0000x reference)
//
#include <hip/hip_runtime.h>
#include <cstdint>

#define LOG2E 1.4426950408889634f

typedef __bf16 bf16x8 __attribute__((ext_vector_type(8)));
typedef float f32x4 __attribute__((ext_vector_type(4)));

#define MFMA16(a,b,c) __builtin_amdgcn_mfma_f32_16x16x32_bf16((a),(b),(c),0,0,0)

// barrier that orders LDS ops only (no vmcnt drain -> global prefetches stay in flight)
#define LDS_BARRIER() asm volatile("s_waitcnt lgkmcnt(0)\n\ts_barrier" ::: "memory")

// workspace layout (in shorts/bf16 elements)
constexpr size_t OFF_XT = 0;              // [2][4][4096][256]  = 8,388,608
constexpr size_t OFF_QT = 8388608;        // [2][4][4096][32]   = 1,048,576  (pre-scaled by log2e)
constexpr size_t OFF_KT = 9437184;        // [2][4][4096][32]   = 1,048,576
constexpr size_t OFF_V  = 10485760;       // [2][4] fragment-tiled: subtile(c16,j32) -> 1KB lane-linear
constexpr size_t OFF_WQ = 18874368;       // 32*256
constexpr size_t OFF_WK = 18882560;       // 32*256
constexpr size_t OFF_WV = 18890752;       // 256*256
constexpr size_t OFF_WC = 18956288;       // 256*512
// total 19,087,360 shorts = 38.2 MB

static __device__ __forceinline__ unsigned short f2b(float a) {
  return __builtin_bit_cast(unsigned short, (__bf16)a);
}
static __device__ __forceinline__ unsigned pk2(float a, float b) {
  return ((unsigned)f2b(b) << 16) | (unsigned)f2b(a);
}

// ---------------------------------------------------------------------------
// Kernel 1: transpose-convert x -> xT[n][c] bf16, and convert weights to bf16
// ---------------------------------------------------------------------------
__global__ __launch_bounds__(256) void prep_kernel(
    const float* __restrict__ x1, const float* __restrict__ x2,
    const float* __restrict__ Wq, const float* __restrict__ Wk,
    const float* __restrict__ Wv, const float* __restrict__ Wc,
    short* __restrict__ ws)
{
  __shared__ float tile[64][65];
  const int tid = threadIdx.x;
  const int blk = blockIdx.x;
  if (blk < 2048) {
    const int nt = blk & 63, ct = (blk >> 6) & 3, b = (blk >> 8) & 3, inp = blk >> 10;
    const float* x = (inp ? x2 : x1) + (size_t)(b * 256 + ct * 64) * 4096 + nt * 64;
#pragma unroll
    for (int p = 0; p < 4; ++p) {
      int r = p * 16 + (tid >> 4);
      float4 v = *(const float4*)(x + (size_t)r * 4096 + (tid & 15) * 4);
      tile[r][(tid & 15) * 4 + 0] = v.x;
      tile[r][(tid & 15) * 4 + 1] = v.y;
      tile[r][(tid & 15) * 4 + 2] = v.z;
      tile[r][(tid & 15) * 4 + 3] = v.w;
    }
    __syncthreads();
    const int n = tid >> 2, c0 = (tid & 3) * 16;
    unsigned u[8];
#pragma unroll
    for (int k = 0; k < 8; ++k)
      u[k] = pk2(tile[c0 + 2 * k][n], tile[c0 + 2 * k + 1][n]);
    short* dst = ws + OFF_XT + (size_t)((inp * 4 + b) * 4096 + nt * 64 + n) * 256 + ct * 64 + c0;
    uint4 s0; s0.x = u[0]; s0.y = u[1]; s0.z = u[2]; s0.w = u[3];
    uint4 s1; s1.x = u[4]; s1.y = u[5]; s1.z = u[6]; s1.w = u[7];
    *(uint4*)(dst) = s0;
    *(uint4*)(dst + 8) = s1;
  } else {
    // weight conversion: [Wq | Wk | Wv | Wc] flat
    int idx = (blk - 2048) * 4096 + tid * 16;
    const float* src; short* dst; int off;
    if (idx < 8192)        { src = Wq; dst = ws + OFF_WQ; off = idx; }
    else if (idx < 16384)  { src = Wk; dst = ws + OFF_WK; off = idx - 8192; }
    else if (idx < 81920)  { src = Wv; dst = ws + OFF_WV; off = idx - 16384; }
    else                   { src = Wc; dst = ws + OFF_WC; off = idx - 81920; }
#pragma unroll
    for (int j = 0; j < 16; ++j) dst[off + j] = (short)f2b(src[off + j]);
  }
}

// ---------------------------------------------------------------------------
// Kernel 2a: Q/K projections -> Qt/Kt [n][32] (Qt scaled by log2e)
// grid 256: blk = inp*128 + b*32 + ntile(128-rows)
// ---------------------------------------------------------------------------
__global__ __launch_bounds__(256) void proj_qk_kernel(
    short* __restrict__ ws, const float* __restrict__ bq, const float* __restrict__ bk)
{
  const int tid = threadIdx.x, lane = tid & 63, wid = tid >> 6;
  const int g = lane >> 4, l15 = lane & 15;
  const int blk = blockIdx.x;
  const int nt = blk & 31, b = (blk >> 5) & 3, inp = blk >> 7;
  const int n0 = nt * 128 + wid * 32;

  const short* xp  = ws + OFF_XT + (size_t)(inp * 4 + b) * (4096 * 256) + (size_t)n0 * 256;
  const short* wqp = ws + OFF_WQ;
  const short* wkp = ws + OFF_WK;
  short* Qt = ws + OFF_QT + (size_t)(inp * 4 + b) * (4096 * 32);
  short* Kt = ws + OFF_KT + (size_t)(inp * 4 + b) * (4096 * 32);

  const f32x4 z4 = {0.f, 0.f, 0.f, 0.f};
  f32x4 aq[2][2], ak[2][2];
#pragma unroll
  for (int i = 0; i < 2; ++i)
#pragma unroll
    for (int j = 0; j < 2; ++j) { aq[i][j] = z4; ak[i][j] = z4; }

#pragma unroll
  for (int ks = 0; ks < 8; ++ks) {
    bf16x8 xa[2];
#pragma unroll
    for (int ns = 0; ns < 2; ++ns)
      xa[ns] = *(const bf16x8*)(xp + (size_t)(ns * 16 + l15) * 256 + ks * 32 + g * 8);
#pragma unroll
    for (int os = 0; os < 2; ++os) {
      bf16x8 wq8 = *(const bf16x8*)(wqp + (size_t)(os * 16 + l15) * 256 + ks * 32 + g * 8);
      bf16x8 wk8 = *(const bf16x8*)(wkp + (size_t)(os * 16 + l15) * 256 + ks * 32 + g * 8);
#pragma unroll
      for (int ns = 0; ns < 2; ++ns) {
        aq[ns][os] = MFMA16(xa[ns], wq8, aq[ns][os]);
        ak[ns][os] = MFMA16(xa[ns], wk8, ak[ns][os]);
      }
    }
  }
  float bqv[2], bkv[2];
#pragma unroll
  for (int os = 0; os < 2; ++os) { bqv[os] = bq[os * 16 + l15]; bkv[os] = bk[os * 16 + l15]; }
#pragma unroll
  for (int ns = 0; ns < 2; ++ns)
#pragma unroll
    for (int os = 0; os < 2; ++os)
#pragma unroll
      for (int r = 0; r < 4; ++r) {
        int n = n0 + ns * 16 + g * 4 + r;
        int o = os * 16 + l15;
        Qt[(size_t)n * 32 + o] = (short)f2b((aq[ns][os][r] + bqv[os]) * LOG2E);
        Kt[(size_t)n * 32 + o] = (short)f2b(ak[ns][os][r] + bkv[os]);
      }
}

// ---------------------------------------------------------------------------
// Kernel 2b: V projection -> fragment-tiled layout:
//   subtile (c16 = c/16, j32 = j/32): 1KB block, lane ℓ holds 8 shorts at
//   c = c16*16 + (ℓ&15), j = j32*32 + (ℓ>>4)*8   (exact MFMA A-fragment)
// grid 512: blk = inp*256 + b*64 + ntile(64-cols)
// ---------------------------------------------------------------------------
__global__ __launch_bounds__(256) void proj_v_kernel(
    short* __restrict__ ws, const float* __restrict__ bv)
{
  const int tid = threadIdx.x, lane = tid & 63, wid = tid >> 6;
  const int g = lane >> 4, l15 = lane & 15;
  const int blk = blockIdx.x;
  const int nt = blk & 63, b = (blk >> 6) & 3, inp = blk >> 8;
  const int n0 = nt * 64;

  const short* xp  = ws + OFF_XT + (size_t)(inp * 4 + b) * (4096 * 256) + (size_t)n0 * 256;
  const short* wvp = ws + OFF_WV;
  short* Vp = ws + OFF_V + (size_t)(inp * 4 + b) * (256 * 4096);

  __shared__ __align__(16) char vl[32768];

  const f32x4 z4 = {0.f, 0.f, 0.f, 0.f};
  f32x4 acc[4][4];
#pragma unroll
  for (int i = 0; i < 4; ++i)
#pragma unroll
    for (int j = 0; j < 4; ++j) acc[i][j] = z4;

#pragma unroll
  for (int ks = 0; ks < 8; ++ks) {
    bf16x8 xa[4];
#pragma unroll
    for (int ns = 0; ns < 4; ++ns)
      xa[ns] = *(const bf16x8*)(xp + (size_t)(ns * 16 + l15) * 256 + ks * 32 + g * 8);
#pragma unroll
    for (int os = 0; os < 4; ++os) {
      bf16x8 wv8 = *(const bf16x8*)(wvp + (size_t)(wid * 64 + os * 16 + l15) * 256 + ks * 32 + g * 8);
#pragma unroll
      for (int ns = 0; ns < 4; ++ns)
        acc[os][ns] = MFMA16(wv8, xa[ns], acc[os][ns]);
    }
  }
  float bvv[4][4];
#pragma unroll
  for (int os = 0; os < 4; ++os)
#pragma unroll
    for (int r = 0; r < 4; ++r) bvv[os][r] = bv[wid * 64 + os * 16 + g * 4 + r];

  char* myl = vl + wid * 8192;
#pragma unroll
  for (int os = 0; os < 4; ++os)
#pragma unroll
    for (int ns = 0; ns < 4; ++ns)
#pragma unroll
      for (int r = 0; r < 4; ++r) {
        int o_loc = os * 16 + g * 4 + r;
        int n_loc = ns * 16 + l15;
        *(short*)(myl + o_loc * 128 + ((n_loc * 2) ^ ((o_loc & 7) << 4))) =
            (short)f2b(acc[os][ns][r] + bvv[os][r]);
      }
  // wave-local fragment readback (same wave -> lgkmcnt ordering suffices)
#pragma unroll
  for (int sc = 0; sc < 4; ++sc)
#pragma unroll
    for (int sj = 0; sj < 2; ++sj) {
      int c_loc = sc * 16 + l15;
      bf16x8 row = *(const bf16x8*)(myl + c_loc * 128 +
                                    (((unsigned)(sj * 64 + g * 16)) ^ ((c_loc & 7) << 4)));
      size_t c16 = (size_t)(wid * 4 + sc);
      size_t j32 = (size_t)(nt * 2 + sj);
      *(bf16x8*)(Vp + (c16 * 128 + j32) * 512 + lane * 8) = row;
    }
}

// ---------------------------------------------------------------------------
// Kernel 3: fused flash attention, 512 threads / 8 waves per block.
// QK^T: wave w -> (i-quarter w&3, j-half w>>2), 2 MFMA.  PV: c-split 8 ways
// (32 c per wave), 16 MFMA.  Ping-pong register prefetch, no-max softmax,
// deferred l reduction.  grid 512: blk = br*256 + b*64 + itile(64 q-rows)
// ---------------------------------------------------------------------------
__global__ __launch_bounds__(512, 4) void attn_kernel(
    short* __restrict__ ws, const float* __restrict__ bc, float* __restrict__ out)
{
  const int tid = threadIdx.x, lane = tid & 63, wid = tid >> 6;   // wid 0..7
  const int g = lane >> 4, l15 = lane & 15;
  const int iq = wid & 3;        // i-quarter for QK^T
  const int jh = wid >> 2;       // j-half for QK^T
  const int blk = blockIdx.x;
  const int itile = blk & 63, b = (blk >> 6) & 3, br = blk >> 8;
  const int i0 = itile * 64;

  __shared__ __align__(16) char sm[35328];
  // loop: [0,16384) = P double-buffer (2 x 64 rows x 128B)
  // epilogue: [0,32768) = attT staging (64 rows x 512B)
  float* l_l  = (float*)(sm + 32768);   // 128 floats: [wave][l15]
  float* part = (float*)(sm + 33280);   // 512 floats: [wave][n]

  const short* Qb  = ws + OFF_QT + (size_t)(br * 4 + b) * (4096 * 32);
  const short* Kb  = ws + OFF_KT + (size_t)(br * 4 + b) * (4096 * 32);
  const short* Vb  = ws + OFF_V  + (size_t)((1 - br) * 4 + b) * (256 * 4096);
  const short* xb  = ws + OFF_XT + (size_t)b * (4096 * 256);   // x1 for both branches
  const short* Wcb = ws + OFF_WC;

  const f32x4 z4 = {0.f, 0.f, 0.f, 0.f};

  // Q fragment for this wave's 16 i-columns (held all pass)
  bf16x8 qf = *(const bf16x8*)(Qb + (size_t)(i0 + iq * 16 + l15) * 32 + g * 8);

  f32x4 oc[2][4];     // O^T [32c (this wave) x 64i]
#pragma unroll
  for (int i = 0; i < 2; ++i)
#pragma unroll
    for (int j = 0; j < 4; ++j) oc[i][j] = z4;
  float l_run = 0.f;  // per-lane partial over this wave's j-half

  // ping-pong prefetch sets
  bf16x8 kf[2][2], va[2][2][2];
#pragma unroll
  for (int jt = 0; jt < 2; ++jt)
    kf[0][jt] = *(const bf16x8*)(Kb + (size_t)(jh * 32 + jt * 16 + l15) * 32 + g * 8);
#pragma unroll
  for (int ks = 0; ks < 2; ++ks)
#pragma unroll
    for (int cs = 0; cs < 2; ++cs)
      va[0][ks][cs] = *(const bf16x8*)(Vb + ((size_t)(wid * 2 + cs) * 128 + ks) * 512 + lane * 8);

  // body: compute tile tcur from set CUR; prefetch tile tnxt into set NXT;
  // P double-buffer index PB (static).
#define ATTN_BODY(tcur, CUR, NXT, tnxt, PB)                                              \
  do {                                                                                   \
    f32x4 st[2];                                                                         \
    _Pragma("unroll")                                                                    \
    for (int jt = 0; jt < 2; ++jt) st[jt] = MFMA16(kf[CUR][jt], qf, z4);                 \
    _Pragma("unroll")                                                                    \
    for (int jt = 0; jt < 2; ++jt)                                                       \
      kf[NXT][jt] = *(const bf16x8*)(Kb + (size_t)((tnxt) * 64 + jh * 32 + jt * 16 + l15) * 32 + g * 8); \
    _Pragma("unroll")                                                                    \
    for (int ks = 0; ks < 2; ++ks)                                                       \
      _Pragma("unroll")                                                                  \
      for (int cs = 0; cs < 2; ++cs)                                                     \
        va[NXT][ks][cs] = *(const bf16x8*)(Vb + ((size_t)(wid * 2 + cs) * 128 +          \
                                                 (size_t)(tnxt) * 2 + ks) * 512 + lane * 8); \
    _Pragma("unroll")                                                                    \
    for (int jt = 0; jt < 2; ++jt)                                                       \
      _Pragma("unroll")                                                                  \
      for (int r = 0; r < 4; ++r) {                                                      \
        float p = exp2f(st[jt][r]);                                                      \
        st[jt][r] = p;                                                                   \
        l_run += p;                                                                      \
      }                                                                                  \
    {                                                                                    \
      char* Pl = sm + (PB) * 8192;                                                       \
      int irow = iq * 16 + l15;                                                          \
      unsigned sw = (unsigned)((irow & 7) << 4);                                         \
      _Pragma("unroll")                                                                  \
      for (int jt = 0; jt < 2; ++jt) {                                                   \
        unsigned long long u =                                                           \
            ((unsigned long long)pk2(st[jt][2], st[jt][3]) << 32) | pk2(st[jt][0], st[jt][1]); \
        *(unsigned long long*)(Pl + irow * 128 +                                         \
                               (((unsigned)(jh * 64 + jt * 32 + g * 8)) ^ sw)) = u;      \
      }                                                                                  \
    }                                                                                    \
    LDS_BARRIER();                                                                       \
    {                                                                                    \
      const char* Pl = sm + (PB) * 8192;                                                 \
      _Pragma("unroll")                                                                  \
      for (int ks = 0; ks < 2; ++ks)                                                     \
        _Pragma("unroll")                                                                \
        for (int it = 0; it < 4; ++it) {                                                 \
          int i = it * 16 + l15;                                                         \
          bf16x8 pb = *(const bf16x8*)(Pl + i * 128 +                                    \
                                       (((unsigned)(ks * 64 + g * 16)) ^ ((i & 7) << 4))); \
          _Pragma("unroll")                                                              \
          for (int cs = 0; cs < 2; ++cs)                                                 \
            oc[cs][it] = MFMA16(va[CUR][ks][cs], pb, oc[cs][it]);                        \
        }                                                                                \
    }                                                                                    \
  } while (0)

  for (int t = 0; t < 64; t += 2) {
    ATTN_BODY(t, 0, 1, t + 1, 0);
    ATTN_BODY(t + 1, 1, 0, (t + 2 < 64) ? (t + 2) : 63, 1);
  }
#undef ATTN_BODY

  // deferred softmax-denominator reduction (linear, so once is exact)
  l_run += __shfl_xor(l_run, 16);
  l_run += __shfl_xor(l_run, 32);

  // ---- epilogue: combine l across j-half wave pairs, normalize, stage attT ----
  if (g == 0) l_l[wid * 16 + l15] = l_run;
  __syncthreads();
  float rl[4];
#pragma unroll
  for (int it = 0; it < 4; ++it)
    rl[it] = 1.f / (l_l[it * 16 + l15] + l_l[(it + 4) * 16 + l15]);

#pragma unroll
  for (int cs = 0; cs < 2; ++cs)
#pragma unroll
    for (int it = 0; it < 4; ++it) {
      f32x4 v = oc[cs][it];
      v *= rl[it];
      int i = it * 16 + l15;
      unsigned byte = (unsigned)(i * 512) +
                      (((unsigned)((wid * 32 + cs * 16 + g * 4) * 2)) ^ ((i & 7) << 4));
      unsigned long long u = ((unsigned long long)pk2(v[2], v[3]) << 32) | pk2(v[0], v[1]);
      *(unsigned long long*)(sm + byte) = u;
    }
  __syncthreads();

  // ---- combine: comb[o,n] = Wc·[x1; att] + bc ; out[n] = sum_o |comb| ----
  f32x4 cc[2][4];
#pragma unroll
  for (int i = 0; i < 2; ++i)
#pragma unroll
    for (int j = 0; j < 4; ++j) cc[i][j] = z4;

#pragma unroll
  for (int ks = 0; ks < 16; ++ks) {
    bf16x8 bfr[4];
#pragma unroll
    for (int ns = 0; ns < 4; ++ns) {
      int n = ns * 16 + l15;
      if (ks < 8)
        bfr[ns] = *(const bf16x8*)(xb + (size_t)(i0 + n) * 256 + ks * 32 + g * 8);
      else
        bfr[ns] = *(const bf16x8*)(sm + n * 512 +
                                   (((unsigned)((ks - 8) * 64 + g * 16)) ^ ((n & 7) << 4)));
    }
#pragma unroll
    for (int os = 0; os < 2; ++os) {
      bf16x8 af = *(const bf16x8*)(Wcb + (size_t)(wid * 32 + os * 16 + l15) * 512 + ks * 32 + g * 8);
#pragma unroll
      for (int ns = 0; ns < 4; ++ns)
        cc[os][ns] = MFMA16(af, bfr[ns], cc[os][ns]);
    }
  }
  float bcv[2][4];
#pragma unroll
  for (int os = 0; os < 2; ++os)
#pragma unroll
    for (int r = 0; r < 4; ++r) bcv[os][r] = bc[wid * 32 + os * 16 + g * 4 + r];

#pragma unroll
  for (int ns = 0; ns < 4; ++ns) {
    float tsum = 0.f;
#pragma unroll
    for (int os = 0; os < 2; ++os)
#pragma unroll
      for (int r = 0; r < 4; ++r)
        tsum += fabsf(cc[os][ns][r] + bcv[os][r]);
    tsum += __shfl_xor(tsum, 16);
    tsum += __shfl_xor(tsum, 32);
    if (g == 0) part[wid * 64 + ns * 16 + l15] = tsum;
  }
  __syncthreads();
  if (tid < 64) {
    float s = 0.f;
#pragma unroll
    for (int w = 0; w < 8; ++w) s += part[w * 64 + tid];
    out[(size_t)br * 16384 + b * 4096 + i0 + tid] = s;
  }
}

// ---------------------------------------------------------------------------
extern "C" void kernel_launch(void* const* d_in, const int* in_sizes, int n_in,
                              void* d_out, int out_size, void* d_ws, size_t ws_size,
                              hipStream_t stream) {
  const float* x1 = (const float*)d_in[0];
  const float* x2 = (const float*)d_in[1];
  const float* Wq = (const float*)d_in[2];
  const float* bq = (const float*)d_in[3];
  const float* Wk = (const float*)d_in[4];
  const float* bk = (const float*)d_in[5];
  const float* Wv = (const float*)d_in[6];
  const float* bv = (const float*)d_in[7];
  const float* Wc = (const float*)d_in[8];
  const float* bc = (const float*)d_in[9];
  short* ws = (short*)d_ws;
  float* out = (float*)d_out;

  prep_kernel<<<2100, 256, 0, stream>>>(x1, x2, Wq, Wk, Wv, Wc, ws);
  proj_qk_kernel<<<256, 256, 0, stream>>>(ws, bq, bk);
  proj_v_kernel<<<512, 256, 0, stream>>>(ws, bv);
  attn_kernel<<<512, 512, 0, stream>>>(ws, bc, out);
}

// Round 6
// 141.094 us; speedup vs baseline: 1.1413x; 1.1413x over previous
//
#include <hip/hip_runtime.h>
#include <cstdint>

#define LOG2E 1.4426950408889634f

typedef __bf16 bf16x8 __attribute__((ext_vector_type(8)));
typedef float f32x4 __attribute__((ext_vector_type(4)));

#define MFMA16(a,b,c) __builtin_amdgcn_mfma_f32_16x16x32_bf16((a),(b),(c),0,0,0)
#define EXP2(x) __builtin_amdgcn_exp2f(x)

// barrier that orders LDS ops only (no vmcnt drain -> global prefetches stay in flight)
#define LDS_BARRIER() asm volatile("s_waitcnt lgkmcnt(0)\n\ts_barrier" ::: "memory")

// workspace layout (in shorts/bf16 elements)
constexpr size_t OFF_XT = 0;              // [2][4][4096][256]  = 8,388,608
constexpr size_t OFF_QT = 8388608;        // [2][4][4096][32]   = 1,048,576  (pre-scaled by log2e)
constexpr size_t OFF_KT = 9437184;        // [2][4][4096][32]   = 1,048,576
constexpr size_t OFF_V  = 10485760;       // [2][4] fragment-tiled: subtile(c16,j32) -> 1KB lane-linear
constexpr size_t OFF_WQ = 18874368;       // 32*256
constexpr size_t OFF_WK = 18882560;       // 32*256
constexpr size_t OFF_WV = 18890752;       // 256*256
constexpr size_t OFF_WC = 18956288;       // 256*512
// total 19,087,360 shorts = 38.2 MB

static __device__ __forceinline__ unsigned short f2b(float a) {
  return __builtin_bit_cast(unsigned short, (__bf16)a);
}
static __device__ __forceinline__ unsigned pk2(float a, float b) {
  return ((unsigned)f2b(b) << 16) | (unsigned)f2b(a);
}

// ---------------------------------------------------------------------------
// Kernel 1: transpose-convert x -> xT[n][c] bf16, and convert weights to bf16
// ---------------------------------------------------------------------------
__global__ __launch_bounds__(256) void prep_kernel(
    const float* __restrict__ x1, const float* __restrict__ x2,
    const float* __restrict__ Wq, const float* __restrict__ Wk,
    const float* __restrict__ Wv, const float* __restrict__ Wc,
    short* __restrict__ ws)
{
  __shared__ float tile[64][65];
  const int tid = threadIdx.x;
  const int blk = blockIdx.x;
  if (blk < 2048) {
    const int nt = blk & 63, ct = (blk >> 6) & 3, b = (blk >> 8) & 3, inp = blk >> 10;
    const float* x = (inp ? x2 : x1) + (size_t)(b * 256 + ct * 64) * 4096 + nt * 64;
#pragma unroll
    for (int p = 0; p < 4; ++p) {
      int r = p * 16 + (tid >> 4);
      float4 v = *(const float4*)(x + (size_t)r * 4096 + (tid & 15) * 4);
      tile[r][(tid & 15) * 4 + 0] = v.x;
      tile[r][(tid & 15) * 4 + 1] = v.y;
      tile[r][(tid & 15) * 4 + 2] = v.z;
      tile[r][(tid & 15) * 4 + 3] = v.w;
    }
    __syncthreads();
    const int n = tid >> 2, c0 = (tid & 3) * 16;
    unsigned u[8];
#pragma unroll
    for (int k = 0; k < 8; ++k)
      u[k] = pk2(tile[c0 + 2 * k][n], tile[c0 + 2 * k + 1][n]);
    short* dst = ws + OFF_XT + (size_t)((inp * 4 + b) * 4096 + nt * 64 + n) * 256 + ct * 64 + c0;
    uint4 s0; s0.x = u[0]; s0.y = u[1]; s0.z = u[2]; s0.w = u[3];
    uint4 s1; s1.x = u[4]; s1.y = u[5]; s1.z = u[6]; s1.w = u[7];
    *(uint4*)(dst) = s0;
    *(uint4*)(dst + 8) = s1;
  } else {
    // weight conversion: [Wq | Wk | Wv | Wc] flat
    int idx = (blk - 2048) * 4096 + tid * 16;
    const float* src; short* dst; int off;
    if (idx < 8192)        { src = Wq; dst = ws + OFF_WQ; off = idx; }
    else if (idx < 16384)  { src = Wk; dst = ws + OFF_WK; off = idx - 8192; }
    else if (idx < 81920)  { src = Wv; dst = ws + OFF_WV; off = idx - 16384; }
    else                   { src = Wc; dst = ws + OFF_WC; off = idx - 81920; }
#pragma unroll
    for (int j = 0; j < 16; ++j) dst[off + j] = (short)f2b(src[off + j]);
  }
}

// ---------------------------------------------------------------------------
// Kernel 2a: Q/K projections -> Qt/Kt [n][32] (Qt scaled by log2e)
// grid 256: blk = inp*128 + b*32 + ntile(128-rows)
// ---------------------------------------------------------------------------
__global__ __launch_bounds__(256) void proj_qk_kernel(
    short* __restrict__ ws, const float* __restrict__ bq, const float* __restrict__ bk)
{
  const int tid = threadIdx.x, lane = tid & 63, wid = tid >> 6;
  const int g = lane >> 4, l15 = lane & 15;
  const int blk = blockIdx.x;
  const int nt = blk & 31, b = (blk >> 5) & 3, inp = blk >> 7;
  const int n0 = nt * 128 + wid * 32;

  const short* xp  = ws + OFF_XT + (size_t)(inp * 4 + b) * (4096 * 256) + (size_t)n0 * 256;
  const short* wqp = ws + OFF_WQ;
  const short* wkp = ws + OFF_WK;
  short* Qt = ws + OFF_QT + (size_t)(inp * 4 + b) * (4096 * 32);
  short* Kt = ws + OFF_KT + (size_t)(inp * 4 + b) * (4096 * 32);

  const f32x4 z4 = {0.f, 0.f, 0.f, 0.f};
  f32x4 aq[2][2], ak[2][2];
#pragma unroll
  for (int i = 0; i < 2; ++i)
#pragma unroll
    for (int j = 0; j < 2; ++j) { aq[i][j] = z4; ak[i][j] = z4; }

#pragma unroll
  for (int ks = 0; ks < 8; ++ks) {
    bf16x8 xa[2];
#pragma unroll
    for (int ns = 0; ns < 2; ++ns)
      xa[ns] = *(const bf16x8*)(xp + (size_t)(ns * 16 + l15) * 256 + ks * 32 + g * 8);
#pragma unroll
    for (int os = 0; os < 2; ++os) {
      bf16x8 wq8 = *(const bf16x8*)(wqp + (size_t)(os * 16 + l15) * 256 + ks * 32 + g * 8);
      bf16x8 wk8 = *(const bf16x8*)(wkp + (size_t)(os * 16 + l15) * 256 + ks * 32 + g * 8);
#pragma unroll
      for (int ns = 0; ns < 2; ++ns) {
        aq[ns][os] = MFMA16(xa[ns], wq8, aq[ns][os]);
        ak[ns][os] = MFMA16(xa[ns], wk8, ak[ns][os]);
      }
    }
  }
  float bqv[2], bkv[2];
#pragma unroll
  for (int os = 0; os < 2; ++os) { bqv[os] = bq[os * 16 + l15]; bkv[os] = bk[os * 16 + l15]; }
#pragma unroll
  for (int ns = 0; ns < 2; ++ns)
#pragma unroll
    for (int os = 0; os < 2; ++os)
#pragma unroll
      for (int r = 0; r < 4; ++r) {
        int n = n0 + ns * 16 + g * 4 + r;
        int o = os * 16 + l15;
        Qt[(size_t)n * 32 + o] = (short)f2b((aq[ns][os][r] + bqv[os]) * LOG2E);
        Kt[(size_t)n * 32 + o] = (short)f2b(ak[ns][os][r] + bkv[os]);
      }
}

// ---------------------------------------------------------------------------
// Kernel 2b: V projection -> fragment-tiled layout:
//   subtile (c16 = c/16, j32 = j/32): 1KB block, lane ℓ holds 8 shorts at
//   c = c16*16 + (ℓ&15), j = j32*32 + (ℓ>>4)*8   (exact MFMA A-fragment)
// grid 512: blk = inp*256 + b*64 + ntile(64-cols)
// ---------------------------------------------------------------------------
__global__ __launch_bounds__(256) void proj_v_kernel(
    short* __restrict__ ws, const float* __restrict__ bv)
{
  const int tid = threadIdx.x, lane = tid & 63, wid = tid >> 6;
  const int g = lane >> 4, l15 = lane & 15;
  const int blk = blockIdx.x;
  const int nt = blk & 63, b = (blk >> 6) & 3, inp = blk >> 8;
  const int n0 = nt * 64;

  const short* xp  = ws + OFF_XT + (size_t)(inp * 4 + b) * (4096 * 256) + (size_t)n0 * 256;
  const short* wvp = ws + OFF_WV;
  short* Vp = ws + OFF_V + (size_t)(inp * 4 + b) * (256 * 4096);

  __shared__ __align__(16) char vl[32768];

  const f32x4 z4 = {0.f, 0.f, 0.f, 0.f};
  f32x4 acc[4][4];
#pragma unroll
  for (int i = 0; i < 4; ++i)
#pragma unroll
    for (int j = 0; j < 4; ++j) acc[i][j] = z4;

#pragma unroll
  for (int ks = 0; ks < 8; ++ks) {
    bf16x8 xa[4];
#pragma unroll
    for (int ns = 0; ns < 4; ++ns)
      xa[ns] = *(const bf16x8*)(xp + (size_t)(ns * 16 + l15) * 256 + ks * 32 + g * 8);
#pragma unroll
    for (int os = 0; os < 4; ++os) {
      bf16x8 wv8 = *(const bf16x8*)(wvp + (size_t)(wid * 64 + os * 16 + l15) * 256 + ks * 32 + g * 8);
#pragma unroll
      for (int ns = 0; ns < 4; ++ns)
        acc[os][ns] = MFMA16(wv8, xa[ns], acc[os][ns]);
    }
  }
  float bvv[4][4];
#pragma unroll
  for (int os = 0; os < 4; ++os)
#pragma unroll
    for (int r = 0; r < 4; ++r) bvv[os][r] = bv[wid * 64 + os * 16 + g * 4 + r];

  char* myl = vl + wid * 8192;
#pragma unroll
  for (int os = 0; os < 4; ++os)
#pragma unroll
    for (int ns = 0; ns < 4; ++ns)
#pragma unroll
      for (int r = 0; r < 4; ++r) {
        int o_loc = os * 16 + g * 4 + r;
        int n_loc = ns * 16 + l15;
        *(short*)(myl + o_loc * 128 + ((n_loc * 2) ^ ((o_loc & 7) << 4))) =
            (short)f2b(acc[os][ns][r] + bvv[os][r]);
      }
  // wave-local fragment readback (same wave -> lgkmcnt ordering suffices)
#pragma unroll
  for (int sc = 0; sc < 4; ++sc)
#pragma unroll
    for (int sj = 0; sj < 2; ++sj) {
      int c_loc = sc * 16 + l15;
      bf16x8 row = *(const bf16x8*)(myl + c_loc * 128 +
                                    (((unsigned)(sj * 64 + g * 16)) ^ ((c_loc & 7) << 4)));
      size_t c16 = (size_t)(wid * 4 + sc);
      size_t j32 = (size_t)(nt * 2 + sj);
      *(bf16x8*)(Vp + (c16 * 128 + j32) * 512 + lane * 8) = row;
    }
}

// ---------------------------------------------------------------------------
// Kernel 3: fused flash attention (swapped QK^T, c-split PV, V from global
// fragments, no-max softmax, raw v_exp_f32). One-step software pipeline:
// at iter t: S(t+1) MFMAs issue first, PV(t) MFMAs run while exp/pack of
// S(t+1) execute on the VALU; single lgkm-barrier per iter.
// grid 512: blk = br*256 + b*64 + itile(64 q-rows)
// ---------------------------------------------------------------------------
__global__ __launch_bounds__(256, 2) void attn_kernel(
    short* __restrict__ ws, const float* __restrict__ bc, float* __restrict__ out)
{
  const int tid = threadIdx.x, lane = tid & 63, wid = tid >> 6;
  const int g = lane >> 4, l15 = lane & 15;
  const int blk = blockIdx.x;
  const int itile = blk & 63, b = (blk >> 6) & 3, br = blk >> 8;
  const int i0 = itile * 64;

  __shared__ __align__(16) char sm[34048];
  // [0,32768): epilogue attT staging; during loop [0,16384) = P double-buffer
  float* l_l  = (float*)(sm + 32768);   // 64 floats
  float* part = (float*)(sm + 33024);   // 256 floats

  const short* Qb  = ws + OFF_QT + (size_t)(br * 4 + b) * (4096 * 32);
  const short* Kb  = ws + OFF_KT + (size_t)(br * 4 + b) * (4096 * 32);
  const short* Vb  = ws + OFF_V  + (size_t)((1 - br) * 4 + b) * (256 * 4096);
  const short* xb  = ws + OFF_XT + (size_t)b * (4096 * 256);   // x1 for both branches
  const short* Wcb = ws + OFF_WC;

  const f32x4 z4 = {0.f, 0.f, 0.f, 0.f};
  const int irow = wid * 16 + l15;
  const unsigned sw = (unsigned)((irow & 7) << 4);

  // Q fragment for this wave's 16 i-columns (held all pass)
  bf16x8 qf = *(const bf16x8*)(Qb + (size_t)(i0 + wid * 16 + l15) * 32 + g * 8);

  f32x4 oc[4][4];     // O^T [64c (this wave) x 64i]
#pragma unroll
  for (int i = 0; i < 4; ++i)
#pragma unroll
    for (int j = 0; j < 4; ++j) oc[i][j] = z4;
  float l_run = 0.f;  // per-lane partial; cross-lane reduced once after loop

  // ---- prologue: S(0) -> P(0) in buf0; prefetch kf<-K(1), va<-V(0) ----
  {
    bf16x8 kt[4];
#pragma unroll
    for (int jt = 0; jt < 4; ++jt)
      kt[jt] = *(const bf16x8*)(Kb + (size_t)(jt * 16 + l15) * 32 + g * 8);
    f32x4 s0[4];
#pragma unroll
    for (int jt = 0; jt < 4; ++jt) s0[jt] = MFMA16(kt[jt], qf, z4);
#pragma unroll
    for (int jt = 0; jt < 4; ++jt) {
#pragma unroll
      for (int r = 0; r < 4; ++r) {
        float p = EXP2(s0[jt][r]);
        s0[jt][r] = p;
        l_run += p;
      }
      unsigned long long u =
          ((unsigned long long)pk2(s0[jt][2], s0[jt][3]) << 32) | pk2(s0[jt][0], s0[jt][1]);
      *(unsigned long long*)(sm + irow * 128 + (((unsigned)(jt * 32 + g * 8)) ^ sw)) = u;
    }
  }

  bf16x8 kf[2][4], va[2][2][4];
#pragma unroll
  for (int jt = 0; jt < 4; ++jt)
    kf[0][jt] = *(const bf16x8*)(Kb + (size_t)(64 + jt * 16 + l15) * 32 + g * 8);
#pragma unroll
  for (int ks = 0; ks < 2; ++ks)
#pragma unroll
    for (int cs = 0; cs < 4; ++cs)
      va[0][ks][cs] = *(const bf16x8*)(Vb + ((size_t)(wid * 4 + cs) * 128 + ks) * 512 + lane * 8);

  LDS_BARRIER();

  // body at tile TC: S(TC+1) first (kf[CUR]); PV(TC) (va[CUR], P buf PBR);
  // prefetch kf[NXT]<-K(TC+2), va[NXT]<-V(TC+1); exp/pack/write P(TC+1)->buf PBW.
#define ATTN_BODY(TC, CUR, NXT, PBR, PBW)                                                \
  do {                                                                                   \
    const int tc = (TC);                                                                 \
    const bool live = (tc < 63);                                                         \
    f32x4 st[4];                                                                         \
    _Pragma("unroll")                                                                    \
    for (int jt = 0; jt < 4; ++jt) st[jt] = MFMA16(kf[CUR][jt], qf, z4);                 \
    {                                                                                    \
      const int t2 = (tc + 2 < 64) ? tc + 2 : 63;                                        \
      const int t1 = (tc + 1 < 64) ? tc + 1 : 63;                                        \
      _Pragma("unroll")                                                                  \
      for (int jt = 0; jt < 4; ++jt)                                                     \
        kf[NXT][jt] = *(const bf16x8*)(Kb + (size_t)(t2 * 64 + jt * 16 + l15) * 32 + g * 8); \
      _Pragma("unroll")                                                                  \
      for (int ks = 0; ks < 2; ++ks)                                                     \
        _Pragma("unroll")                                                                \
        for (int cs = 0; cs < 4; ++cs)                                                   \
          va[NXT][ks][cs] = *(const bf16x8*)(Vb + ((size_t)(wid * 4 + cs) * 128 +        \
                                                   (size_t)t1 * 2 + ks) * 512 + lane * 8); \
    }                                                                                    \
    __builtin_amdgcn_s_setprio(1);                                                       \
    {                                                                                    \
      const char* Pl = sm + (PBR) * 8192;                                                \
      _Pragma("unroll")                                                                  \
      for (int ks = 0; ks < 2; ++ks)                                                     \
        _Pragma("unroll")                                                                \
        for (int it = 0; it < 4; ++it) {                                                 \
          int i = it * 16 + l15;                                                         \
          bf16x8 pb = *(const bf16x8*)(Pl + i * 128 +                                    \
                                       (((unsigned)(ks * 64 + g * 16)) ^ ((i & 7) << 4))); \
          _Pragma("unroll")                                                              \
          for (int cs = 0; cs < 4; ++cs)                                                 \
            oc[cs][it] = MFMA16(va[CUR][ks][cs], pb, oc[cs][it]);                        \
        }                                                                                \
    }                                                                                    \
    __builtin_amdgcn_s_setprio(0);                                                       \
    if (live) {                                                                          \
      char* Pw = sm + (PBW) * 8192;                                                      \
      _Pragma("unroll")                                                                  \
      for (int jt = 0; jt < 4; ++jt) {                                                   \
        _Pragma("unroll")                                                                \
        for (int r = 0; r < 4; ++r) {                                                    \
          float p = EXP2(st[jt][r]);                                                     \
          st[jt][r] = p;                                                                 \
          l_run += p;                                                                    \
        }                                                                                \
        unsigned long long u =                                                           \
            ((unsigned long long)pk2(st[jt][2], st[jt][3]) << 32) | pk2(st[jt][0], st[jt][1]); \
        *(unsigned long long*)(Pw + irow * 128 + (((unsigned)(jt * 32 + g * 8)) ^ sw)) = u; \
      }                                                                                  \
    }                                                                                    \
    LDS_BARRIER();                                                                       \
  } while (0)

  for (int t = 0; t < 64; t += 2) {
    ATTN_BODY(t, 0, 1, 0, 1);
    ATTN_BODY(t + 1, 1, 0, 1, 0);
  }
#undef ATTN_BODY

  // deferred softmax-denominator reduction (linear, so once is exact)
  l_run += __shfl_xor(l_run, 16);
  l_run += __shfl_xor(l_run, 32);

  // ---- epilogue: normalize, stage attT[i][c] into LDS ----
  if (g == 0) l_l[irow] = l_run;
  __syncthreads();
  float rl[4];
#pragma unroll
  for (int it = 0; it < 4; ++it) rl[it] = 1.f / l_l[it * 16 + l15];

#pragma unroll
  for (int cs = 0; cs < 4; ++cs)
#pragma unroll
    for (int it = 0; it < 4; ++it) {
      f32x4 v = oc[cs][it];
      v *= rl[it];
      int i = it * 16 + l15;
      unsigned byte = (unsigned)(i * 512) +
                      (((unsigned)((wid * 64 + cs * 16 + g * 4) * 2)) ^ ((i & 7) << 4));
      unsigned long long u = ((unsigned long long)pk2(v[2], v[3]) << 32) | pk2(v[0], v[1]);
      *(unsigned long long*)(sm + byte) = u;
    }
  __syncthreads();

  // ---- combine: comb[o,n] = Wc·[x1; att] + bc ; out[n] = sum_o |comb| ----
  f32x4 cc[4][4];
#pragma unroll
  for (int i = 0; i < 4; ++i)
#pragma unroll
    for (int j = 0; j < 4; ++j) cc[i][j] = z4;

#pragma unroll
  for (int ks = 0; ks < 16; ++ks) {
    bf16x8 bfr[4];
#pragma unroll
    for (int ns = 0; ns < 4; ++ns) {
      int n = ns * 16 + l15;
      if (ks < 8)
        bfr[ns] = *(const bf16x8*)(xb + (size_t)(i0 + n) * 256 + ks * 32 + g * 8);
      else
        bfr[ns] = *(const bf16x8*)(sm + n * 512 +
                                   (((unsigned)((ks - 8) * 64 + g * 16)) ^ ((n & 7) << 4)));
    }
#pragma unroll
    for (int os = 0; os < 4; ++os) {
      bf16x8 af = *(const bf16x8*)(Wcb + (size_t)(wid * 64 + os * 16 + l15) * 512 + ks * 32 + g * 8);
#pragma unroll
      for (int ns = 0; ns < 4; ++ns)
        cc[os][ns] = MFMA16(af, bfr[ns], cc[os][ns]);
    }
  }
  float bcv[4][4];
#pragma unroll
  for (int os = 0; os < 4; ++os)
#pragma unroll
    for (int r = 0; r < 4; ++r) bcv[os][r] = bc[wid * 64 + os * 16 + g * 4 + r];

#pragma unroll
  for (int ns = 0; ns < 4; ++ns) {
    float tsum = 0.f;
#pragma unroll
    for (int os = 0; os < 4; ++os)
#pragma unroll
      for (int r = 0; r < 4; ++r)
        tsum += fabsf(cc[os][ns][r] + bcv[os][r]);
    tsum += __shfl_xor(tsum, 16);
    tsum += __shfl_xor(tsum, 32);
    if (g == 0) part[wid * 64 + ns * 16 + l15] = tsum;
  }
  __syncthreads();
  if (tid < 64) {
    float s = part[tid] + part[64 + tid] + part[128 + tid] + part[192 + tid];
    out[(size_t)br * 16384 + b * 4096 + i0 + tid] = s;
  }
}

// ---------------------------------------------------------------------------
extern "C" void kernel_launch(void* const* d_in, const int* in_sizes, int n_in,
                              void* d_out, int out_size, void* d_ws, size_t ws_size,
                              hipStream_t stream) {
  const float* x1 = (const float*)d_in[0];
  const float* x2 = (const float*)d_in[1];
  const float* Wq = (const float*)d_in[2];
  const float* bq = (const float*)d_in[3];
  const float* Wk = (const float*)d_in[4];
  const float* bk = (const float*)d_in[5];
  const float* Wv = (const float*)d_in[6];
  const float* bv = (const float*)d_in[7];
  const float* Wc = (const float*)d_in[8];
  const float* bc = (const float*)d_in[9];
  short* ws = (short*)d_ws;
  float* out = (float*)d_out;

  prep_kernel<<<2100, 256, 0, stream>>>(x1, x2, Wq, Wk, Wv, Wc, ws);
  proj_qk_kernel<<<256, 256, 0, stream>>>(ws, bq, bk);
  proj_v_kernel<<<512, 256, 0, stream>>>(ws, bv);
  attn_kernel<<<512, 256, 0, stream>>>(ws, bc, out);
}

// Round 7
// 135.769 us; speedup vs baseline: 1.1861x; 1.0392x over previous
//
#include <hip/hip_runtime.h>
#include <cstdint>

#define LOG2E 1.4426950408889634f

typedef __bf16 bf16x8 __attribute__((ext_vector_type(8)));
typedef float f32x4 __attribute__((ext_vector_type(4)));

#define MFMA16(a,b,c) __builtin_amdgcn_mfma_f32_16x16x32_bf16((a),(b),(c),0,0,0)
#define EXP2(x) __builtin_amdgcn_exp2f(x)

// barrier that orders LDS ops only (no vmcnt drain -> global prefetches stay in flight)
#define LDS_BARRIER() asm volatile("s_waitcnt lgkmcnt(0)\n\ts_barrier" ::: "memory")

// workspace layout (in shorts/bf16 elements)
constexpr size_t OFF_XT = 0;              // [2][4][4096][256]  = 8,388,608
constexpr size_t OFF_QT = 8388608;        // [2][4][4096][32]   = 1,048,576  (pre-scaled by log2e)
constexpr size_t OFF_KT = 9437184;        // [2][4][4096][32]   = 1,048,576
constexpr size_t OFF_V  = 10485760;       // [2][4] fragment-tiled: subtile(c16,j32) -> 1KB lane-linear
constexpr size_t OFF_WQ = 18874368;       // 32*256
constexpr size_t OFF_WK = 18882560;       // 32*256
constexpr size_t OFF_WV = 18890752;       // 256*256
constexpr size_t OFF_WC = 18956288;       // 256*512
// total 19,087,360 shorts = 38.2 MB

static __device__ __forceinline__ unsigned short f2b(float a) {
  return __builtin_bit_cast(unsigned short, (__bf16)a);
}
static __device__ __forceinline__ unsigned pk2(float a, float b) {
  return ((unsigned)f2b(b) << 16) | (unsigned)f2b(a);
}

// ---------------------------------------------------------------------------
// Kernel 1: transpose-convert x -> xT[n][c] bf16, and convert weights to bf16
// ---------------------------------------------------------------------------
__global__ __launch_bounds__(256) void prep_kernel(
    const float* __restrict__ x1, const float* __restrict__ x2,
    const float* __restrict__ Wq, const float* __restrict__ Wk,
    const float* __restrict__ Wv, const float* __restrict__ Wc,
    short* __restrict__ ws)
{
  __shared__ float tile[64][65];
  const int tid = threadIdx.x;
  const int blk = blockIdx.x;
  if (blk < 2048) {
    const int nt = blk & 63, ct = (blk >> 6) & 3, b = (blk >> 8) & 3, inp = blk >> 10;
    const float* x = (inp ? x2 : x1) + (size_t)(b * 256 + ct * 64) * 4096 + nt * 64;
#pragma unroll
    for (int p = 0; p < 4; ++p) {
      int r = p * 16 + (tid >> 4);
      float4 v = *(const float4*)(x + (size_t)r * 4096 + (tid & 15) * 4);
      tile[r][(tid & 15) * 4 + 0] = v.x;
      tile[r][(tid & 15) * 4 + 1] = v.y;
      tile[r][(tid & 15) * 4 + 2] = v.z;
      tile[r][(tid & 15) * 4 + 3] = v.w;
    }
    __syncthreads();
    const int n = tid >> 2, c0 = (tid & 3) * 16;
    unsigned u[8];
#pragma unroll
    for (int k = 0; k < 8; ++k)
      u[k] = pk2(tile[c0 + 2 * k][n], tile[c0 + 2 * k + 1][n]);
    short* dst = ws + OFF_XT + (size_t)((inp * 4 + b) * 4096 + nt * 64 + n) * 256 + ct * 64 + c0;
    uint4 s0; s0.x = u[0]; s0.y = u[1]; s0.z = u[2]; s0.w = u[3];
    uint4 s1; s1.x = u[4]; s1.y = u[5]; s1.z = u[6]; s1.w = u[7];
    *(uint4*)(dst) = s0;
    *(uint4*)(dst + 8) = s1;
  } else {
    // weight conversion: [Wq | Wk | Wv | Wc] flat
    int idx = (blk - 2048) * 4096 + tid * 16;
    const float* src; short* dst; int off;
    if (idx < 8192)        { src = Wq; dst = ws + OFF_WQ; off = idx; }
    else if (idx < 16384)  { src = Wk; dst = ws + OFF_WK; off = idx - 8192; }
    else if (idx < 81920)  { src = Wv; dst = ws + OFF_WV; off = idx - 16384; }
    else                   { src = Wc; dst = ws + OFF_WC; off = idx - 81920; }
#pragma unroll
    for (int j = 0; j < 16; ++j) dst[off + j] = (short)f2b(src[off + j]);
  }
}

// ---------------------------------------------------------------------------
// Kernel 2 (merged): blk<256 -> Q/K projections; blk>=256 -> V projection.
// ---------------------------------------------------------------------------
static __device__ __forceinline__ void proj_qk_body(
    short* __restrict__ ws, const float* __restrict__ bq, const float* __restrict__ bk,
    int blk, int tid)
{
  const int lane = tid & 63, wid = tid >> 6;
  const int g = lane >> 4, l15 = lane & 15;
  const int nt = blk & 31, b = (blk >> 5) & 3, inp = blk >> 7;
  const int n0 = nt * 128 + wid * 32;

  const short* xp  = ws + OFF_XT + (size_t)(inp * 4 + b) * (4096 * 256) + (size_t)n0 * 256;
  const short* wqp = ws + OFF_WQ;
  const short* wkp = ws + OFF_WK;
  short* Qt = ws + OFF_QT + (size_t)(inp * 4 + b) * (4096 * 32);
  short* Kt = ws + OFF_KT + (size_t)(inp * 4 + b) * (4096 * 32);

  const f32x4 z4 = {0.f, 0.f, 0.f, 0.f};
  f32x4 aq[2][2], ak[2][2];
#pragma unroll
  for (int i = 0; i < 2; ++i)
#pragma unroll
    for (int j = 0; j < 2; ++j) { aq[i][j] = z4; ak[i][j] = z4; }

#pragma unroll
  for (int ks = 0; ks < 8; ++ks) {
    bf16x8 xa[2];
#pragma unroll
    for (int ns = 0; ns < 2; ++ns)
      xa[ns] = *(const bf16x8*)(xp + (size_t)(ns * 16 + l15) * 256 + ks * 32 + g * 8);
#pragma unroll
    for (int os = 0; os < 2; ++os) {
      bf16x8 wq8 = *(const bf16x8*)(wqp + (size_t)(os * 16 + l15) * 256 + ks * 32 + g * 8);
      bf16x8 wk8 = *(const bf16x8*)(wkp + (size_t)(os * 16 + l15) * 256 + ks * 32 + g * 8);
#pragma unroll
      for (int ns = 0; ns < 2; ++ns) {
        aq[ns][os] = MFMA16(xa[ns], wq8, aq[ns][os]);
        ak[ns][os] = MFMA16(xa[ns], wk8, ak[ns][os]);
      }
    }
  }
  float bqv[2], bkv[2];
#pragma unroll
  for (int os = 0; os < 2; ++os) { bqv[os] = bq[os * 16 + l15]; bkv[os] = bk[os * 16 + l15]; }
#pragma unroll
  for (int ns = 0; ns < 2; ++ns)
#pragma unroll
    for (int os = 0; os < 2; ++os)
#pragma unroll
      for (int r = 0; r < 4; ++r) {
        int n = n0 + ns * 16 + g * 4 + r;
        int o = os * 16 + l15;
        Qt[(size_t)n * 32 + o] = (short)f2b((aq[ns][os][r] + bqv[os]) * LOG2E);
        Kt[(size_t)n * 32 + o] = (short)f2b(ak[ns][os][r] + bkv[os]);
      }
}

static __device__ __forceinline__ void proj_v_body(
    short* __restrict__ ws, const float* __restrict__ bv, char* vl, int blk, int tid)
{
  const int lane = tid & 63, wid = tid >> 6;
  const int g = lane >> 4, l15 = lane & 15;
  const int nt = blk & 63, b = (blk >> 6) & 3, inp = blk >> 8;
  const int n0 = nt * 64;

  const short* xp  = ws + OFF_XT + (size_t)(inp * 4 + b) * (4096 * 256) + (size_t)n0 * 256;
  const short* wvp = ws + OFF_WV;
  short* Vp = ws + OFF_V + (size_t)(inp * 4 + b) * (256 * 4096);

  const f32x4 z4 = {0.f, 0.f, 0.f, 0.f};
  f32x4 acc[4][4];
#pragma unroll
  for (int i = 0; i < 4; ++i)
#pragma unroll
    for (int j = 0; j < 4; ++j) acc[i][j] = z4;

#pragma unroll
  for (int ks = 0; ks < 8; ++ks) {
    bf16x8 xa[4];
#pragma unroll
    for (int ns = 0; ns < 4; ++ns)
      xa[ns] = *(const bf16x8*)(xp + (size_t)(ns * 16 + l15) * 256 + ks * 32 + g * 8);
#pragma unroll
    for (int os = 0; os < 4; ++os) {
      bf16x8 wv8 = *(const bf16x8*)(wvp + (size_t)(wid * 64 + os * 16 + l15) * 256 + ks * 32 + g * 8);
#pragma unroll
      for (int ns = 0; ns < 4; ++ns)
        acc[os][ns] = MFMA16(wv8, xa[ns], acc[os][ns]);
    }
  }
  float bvv[4][4];
#pragma unroll
  for (int os = 0; os < 4; ++os)
#pragma unroll
    for (int r = 0; r < 4; ++r) bvv[os][r] = bv[wid * 64 + os * 16 + g * 4 + r];

  char* myl = vl + wid * 8192;
#pragma unroll
  for (int os = 0; os < 4; ++os)
#pragma unroll
    for (int ns = 0; ns < 4; ++ns)
#pragma unroll
      for (int r = 0; r < 4; ++r) {
        int o_loc = os * 16 + g * 4 + r;
        int n_loc = ns * 16 + l15;
        *(short*)(myl + o_loc * 128 + ((n_loc * 2) ^ ((o_loc & 7) << 4))) =
            (short)f2b(acc[os][ns][r] + bvv[os][r]);
      }
  // wave-local fragment readback (same wave -> lgkmcnt ordering suffices)
#pragma unroll
  for (int sc = 0; sc < 4; ++sc)
#pragma unroll
    for (int sj = 0; sj < 2; ++sj) {
      int c_loc = sc * 16 + l15;
      bf16x8 row = *(const bf16x8*)(myl + c_loc * 128 +
                                    (((unsigned)(sj * 64 + g * 16)) ^ ((c_loc & 7) << 4)));
      size_t c16 = (size_t)(wid * 4 + sc);
      size_t j32 = (size_t)(nt * 2 + sj);
      *(bf16x8*)(Vp + (c16 * 128 + j32) * 512 + lane * 8) = row;
    }
}

__global__ __launch_bounds__(256) void proj_kernel(
    short* __restrict__ ws, const float* __restrict__ bq,
    const float* __restrict__ bk, const float* __restrict__ bv)
{
  __shared__ __align__(16) char vl[32768];
  const int tid = threadIdx.x, blk = blockIdx.x;
  if (blk < 256) proj_qk_body(ws, bq, bk, blk, tid);
  else           proj_v_body(ws, bv, vl, blk - 256, tid);
}

// ---------------------------------------------------------------------------
// Kernel 3: fused flash attention (swapped QK^T, c-split PV, V from global
// fragments, no-max softmax, raw v_exp_f32, 1-step software pipeline).
// XCD-group swizzle: the 64 blocks of one (br,b) group land on one XCD so
// its L2 privately holds that group's K/V/Q/x working set (~4.5 MB).
// grid 512: bid = br*256 + b*64 + itile(64 q-rows)
// ---------------------------------------------------------------------------
__global__ __launch_bounds__(256, 2) void attn_kernel(
    short* __restrict__ ws, const float* __restrict__ bc, float* __restrict__ out)
{
  const int tid = threadIdx.x, lane = tid & 63, wid = tid >> 6;
  const int g = lane >> 4, l15 = lane & 15;
  // XCD-aware swizzle (8 XCDs, 512 blocks): group g = bid>>6 constant per XCD
  const int bid = ((blockIdx.x & 7) << 6) | (blockIdx.x >> 3);
  const int itile = bid & 63, b = (bid >> 6) & 3, br = bid >> 8;
  const int i0 = itile * 64;

  __shared__ __align__(16) char sm[34048];
  // [0,32768): epilogue attT staging; during loop [0,16384) = P double-buffer
  float* l_l  = (float*)(sm + 32768);   // 64 floats
  float* part = (float*)(sm + 33024);   // 256 floats

  const short* Qb  = ws + OFF_QT + (size_t)(br * 4 + b) * (4096 * 32);
  const short* Kb  = ws + OFF_KT + (size_t)(br * 4 + b) * (4096 * 32);
  const short* Vb  = ws + OFF_V  + (size_t)((1 - br) * 4 + b) * (256 * 4096);
  const short* xb  = ws + OFF_XT + (size_t)b * (4096 * 256);   // x1 for both branches
  const short* Wcb = ws + OFF_WC;

  const f32x4 z4 = {0.f, 0.f, 0.f, 0.f};
  const int irow = wid * 16 + l15;
  const unsigned sw = (unsigned)((irow & 7) << 4);

  // Q fragment for this wave's 16 i-columns (held all pass)
  bf16x8 qf = *(const bf16x8*)(Qb + (size_t)(i0 + wid * 16 + l15) * 32 + g * 8);

  f32x4 oc[4][4];     // O^T [64c (this wave) x 64i]
#pragma unroll
  for (int i = 0; i < 4; ++i)
#pragma unroll
    for (int j = 0; j < 4; ++j) oc[i][j] = z4;
  float l_run = 0.f;  // per-lane partial; cross-lane reduced once after loop

  // ---- prologue: S(0) -> P(0) in buf0; prefetch kf<-K(1), va<-V(0) ----
  {
    bf16x8 kt[4];
#pragma unroll
    for (int jt = 0; jt < 4; ++jt)
      kt[jt] = *(const bf16x8*)(Kb + (size_t)(jt * 16 + l15) * 32 + g * 8);
    f32x4 s0[4];
#pragma unroll
    for (int jt = 0; jt < 4; ++jt) s0[jt] = MFMA16(kt[jt], qf, z4);
#pragma unroll
    for (int jt = 0; jt < 4; ++jt) {
#pragma unroll
      for (int r = 0; r < 4; ++r) {
        float p = EXP2(s0[jt][r]);
        s0[jt][r] = p;
        l_run += p;
      }
      unsigned long long u =
          ((unsigned long long)pk2(s0[jt][2], s0[jt][3]) << 32) | pk2(s0[jt][0], s0[jt][1]);
      *(unsigned long long*)(sm + irow * 128 + (((unsigned)(jt * 32 + g * 8)) ^ sw)) = u;
    }
  }

  bf16x8 kf[2][4], va[2][2][4];
#pragma unroll
  for (int jt = 0; jt < 4; ++jt)
    kf[0][jt] = *(const bf16x8*)(Kb + (size_t)(64 + jt * 16 + l15) * 32 + g * 8);
#pragma unroll
  for (int ks = 0; ks < 2; ++ks)
#pragma unroll
    for (int cs = 0; cs < 4; ++cs)
      va[0][ks][cs] = *(const bf16x8*)(Vb + ((size_t)(wid * 4 + cs) * 128 + ks) * 512 + lane * 8);

  LDS_BARRIER();

  // body at tile TC: S(TC+1) first (kf[CUR]); PV(TC) (va[CUR], P buf PBR);
  // prefetch kf[NXT]<-K(TC+2) [PREFK], va[NXT]<-V(TC+1) [PREFV];
  // exp/pack/write P(TC+1)->buf PBW [DO_S].
#define ATTN_BODY(TC, CUR, NXT, PBR, PBW, DO_S, PREFK, PREFV)                            \
  do {                                                                                   \
    f32x4 st[4];                                                                         \
    if (DO_S) {                                                                          \
      _Pragma("unroll")                                                                  \
      for (int jt = 0; jt < 4; ++jt) st[jt] = MFMA16(kf[CUR][jt], qf, z4);               \
    }                                                                                    \
    if (PREFK) {                                                                         \
      _Pragma("unroll")                                                                  \
      for (int jt = 0; jt < 4; ++jt)                                                     \
        kf[NXT][jt] = *(const bf16x8*)(Kb + (size_t)(((TC) + 2) * 64 + jt * 16 + l15) * 32 + g * 8); \
    }                                                                                    \
    if (PREFV) {                                                                         \
      _Pragma("unroll")                                                                  \
      for (int ks = 0; ks < 2; ++ks)                                                     \
        _Pragma("unroll")                                                                \
        for (int cs = 0; cs < 4; ++cs)                                                   \
          va[NXT][ks][cs] = *(const bf16x8*)(Vb + ((size_t)(wid * 4 + cs) * 128 +        \
                                                   (size_t)((TC) + 1) * 2 + ks) * 512 + lane * 8); \
    }                                                                                    \
    __builtin_amdgcn_s_setprio(1);                                                       \
    {                                                                                    \
      const char* Pl = sm + (PBR) * 8192;                                                \
      _Pragma("unroll")                                                                  \
      for (int ks = 0; ks < 2; ++ks)                                                     \
        _Pragma("unroll")                                                                \
        for (int it = 0; it < 4; ++it) {                                                 \
          int i = it * 16 + l15;                                                         \
          bf16x8 pb = *(const bf16x8*)(Pl + i * 128 +                                    \
                                       (((unsigned)(ks * 64 + g * 16)) ^ ((i & 7) << 4))); \
          _Pragma("unroll")                                                              \
          for (int cs = 0; cs < 4; ++cs)                                                 \
            oc[cs][it] = MFMA16(va[CUR][ks][cs], pb, oc[cs][it]);                        \
        }                                                                                \
    }                                                                                    \
    __builtin_amdgcn_s_setprio(0);                                                       \
    if (DO_S) {                                                                          \
      char* Pw = sm + (PBW) * 8192;                                                      \
      _Pragma("unroll")                                                                  \
      for (int jt = 0; jt < 4; ++jt) {                                                   \
        _Pragma("unroll")                                                                \
        for (int r = 0; r < 4; ++r) {                                                    \
          float p = EXP2(st[jt][r]);                                                     \
          st[jt][r] = p;                                                                 \
          l_run += p;                                                                    \
        }                                                                                \
        unsigned long long u =                                                           \
            ((unsigned long long)pk2(st[jt][2], st[jt][3]) << 32) | pk2(st[jt][0], st[jt][1]); \
        *(unsigned long long*)(Pw + irow * 128 + (((unsigned)(jt * 32 + g * 8)) ^ sw)) = u; \
      }                                                                                  \
    }                                                                                    \
    LDS_BARRIER();                                                                       \
  } while (0)

  for (int t = 0; t < 62; t += 2) {
    ATTN_BODY(t, 0, 1, 0, 1, 1, 1, 1);
    ATTN_BODY(t + 1, 1, 0, 1, 0, 1, 1, 1);
  }
  ATTN_BODY(62, 0, 1, 0, 1, 1, 0, 1);   // S(63), PV(62), fetch V(63) only
  ATTN_BODY(63, 1, 0, 1, 0, 0, 0, 0);   // PV(63) only
#undef ATTN_BODY

  // deferred softmax-denominator reduction (linear, so once is exact)
  l_run += __shfl_xor(l_run, 16);
  l_run += __shfl_xor(l_run, 32);

  // ---- epilogue: normalize, stage attT[i][c] into LDS ----
  if (g == 0) l_l[irow] = l_run;
  __syncthreads();
  float rl[4];
#pragma unroll
  for (int it = 0; it < 4; ++it) rl[it] = 1.f / l_l[it * 16 + l15];

#pragma unroll
  for (int cs = 0; cs < 4; ++cs)
#pragma unroll
    for (int it = 0; it < 4; ++it) {
      f32x4 v = oc[cs][it];
      v *= rl[it];
      int i = it * 16 + l15;
      unsigned byte = (unsigned)(i * 512) +
                      (((unsigned)((wid * 64 + cs * 16 + g * 4) * 2)) ^ ((i & 7) << 4));
      unsigned long long u = ((unsigned long long)pk2(v[2], v[3]) << 32) | pk2(v[0], v[1]);
      *(unsigned long long*)(sm + byte) = u;
    }
  __syncthreads();

  // ---- combine: comb[o,n] = Wc·[x1; att] + bc ; out[n] = sum_o |comb| ----
  f32x4 cc[4][4];
#pragma unroll
  for (int i = 0; i < 4; ++i)
#pragma unroll
    for (int j = 0; j < 4; ++j) cc[i][j] = z4;

#pragma unroll
  for (int ks = 0; ks < 16; ++ks) {
    bf16x8 bfr[4];
#pragma unroll
    for (int ns = 0; ns < 4; ++ns) {
      int n = ns * 16 + l15;
      if (ks < 8)
        bfr[ns] = *(const bf16x8*)(xb + (size_t)(i0 + n) * 256 + ks * 32 + g * 8);
      else
        bfr[ns] = *(const bf16x8*)(sm + n * 512 +
                                   (((unsigned)((ks - 8) * 64 + g * 16)) ^ ((n & 7) << 4)));
    }
#pragma unroll
    for (int os = 0; os < 4; ++os) {
      bf16x8 af = *(const bf16x8*)(Wcb + (size_t)(wid * 64 + os * 16 + l15) * 512 + ks * 32 + g * 8);
#pragma unroll
      for (int ns = 0; ns < 4; ++ns)
        cc[os][ns] = MFMA16(af, bfr[ns], cc[os][ns]);
    }
  }
  float bcv[4][4];
#pragma unroll
  for (int os = 0; os < 4; ++os)
#pragma unroll
    for (int r = 0; r < 4; ++r) bcv[os][r] = bc[wid * 64 + os * 16 + g * 4 + r];

#pragma unroll
  for (int ns = 0; ns < 4; ++ns) {
    float tsum = 0.f;
#pragma unroll
    for (int os = 0; os < 4; ++os)
#pragma unroll
      for (int r = 0; r < 4; ++r)
        tsum += fabsf(cc[os][ns][r] + bcv[os][r]);
    tsum += __shfl_xor(tsum, 16);
    tsum += __shfl_xor(tsum, 32);
    if (g == 0) part[wid * 64 + ns * 16 + l15] = tsum;
  }
  __syncthreads();
  if (tid < 64) {
    float s = part[tid] + part[64 + tid] + part[128 + tid] + part[192 + tid];
    out[(size_t)br * 16384 + b * 4096 + i0 + tid] = s;
  }
}

// ---------------------------------------------------------------------------
extern "C" void kernel_launch(void* const* d_in, const int* in_sizes, int n_in,
                              void* d_out, int out_size, void* d_ws, size_t ws_size,
                              hipStream_t stream) {
  const float* x1 = (const float*)d_in[0];
  const float* x2 = (const float*)d_in[1];
  const float* Wq = (const float*)d_in[2];
  const float* bq = (const float*)d_in[3];
  const float* Wk = (const float*)d_in[4];
  const float* bk = (const float*)d_in[5];
  const float* Wv = (const float*)d_in[6];
  const float* bv = (const float*)d_in[7];
  const float* Wc = (const float*)d_in[8];
  const float* bc = (const float*)d_in[9];
  short* ws = (short*)d_ws;
  float* out = (float*)d_out;

  prep_kernel<<<2100, 256, 0, stream>>>(x1, x2, Wq, Wk, Wv, Wc, ws);
  proj_kernel<<<768, 256, 0, stream>>>(ws, bq, bk, bv);
  attn_kernel<<<512, 256, 0, stream>>>(ws, bc, out);
}